// Round 11
// baseline (40.793 us; speedup 1.0000x reference)
//
#include <hip/hip_runtime.h>
#include <hip/hip_bf16.h>
#include <math.h>

#define N_STATIONS 276
#define CTX 384
#define TGT 96
#define BATCH 4096
#define NTILE_N 6                      // 96 cols / 16
#define NBLK (N_STATIONS * NTILE_N)    // 1656 one-wave blocks
#define CPX (NBLK / 8)                 // 207 — 1656 divisible by 8, swizzle bijective
#define LISTMAX 256

typedef __attribute__((ext_vector_type(8))) short bf16x8;   // 8 bf16 (4 VGPRs)
typedef __attribute__((ext_vector_type(4))) float f32x4;    // MFMA acc

__device__ __forceinline__ short f2bf(float f) {            // HW RNE cvt
    return (short)__builtin_bit_cast(unsigned short, __float2bfloat16(f));
}
__device__ __forceinline__ float bf2f(short h) {
    unsigned u = ((unsigned)(unsigned short)h) << 16;
    return __builtin_bit_cast(float, u);
}

// W float4-pair -> bf16 hi + lo fragments (W ~= hi + lo)
__device__ __forceinline__ void cvt_hilo(float4 a, float4 b, bf16x8& hi, bf16x8& lo) {
    float f[8] = {a.x, a.y, a.z, a.w, b.x, b.y, b.z, b.w};
#pragma unroll
    for (int i = 0; i < 8; ++i) {
        short h = f2bf(f[i]);
        hi[i] = h;
        lo[i] = f2bf(f[i] - bf2f(h));
    }
}
// z float4-pair -> normalized bf16 fragment: zn = z*inv + nb  (nb = -lc*inv)
__device__ __forceinline__ bf16x8 cvt_norm(float4 a, float4 b, float inv, float nb) {
    float f[8] = {a.x, a.y, a.z, a.w, b.x, b.y, b.z, b.w};
    bf16x8 r;
#pragma unroll
    for (int i = 0; i < 8; ++i) r[i] = f2bf(fmaf(f[i], inv, nb));
    return r;
}

// ---------- single fused kernel: one wave per (station x 16-col tile) ----------
// Wave builds its station's sample list via ballot scan (no build kernel),
// then MFMA: D(16 samples x 16 cols) += A(16x32) * B(32x16) over 12 K-steps.
// Layouts verified by R10 pass: A row=l&15 (sample), B col=l&15 (out col),
// D row=(l>>4)*4+r (sample), col=l&15.
__global__ __launch_bounds__(64) void nlinear_fused(
    const float* __restrict__ z,        // (BATCH, CTX)
    const int*   __restrict__ stations, // (BATCH,)
    const float* __restrict__ W,        // (N_STATIONS, TGT, CTX)
    const float* __restrict__ bias,     // (N_STATIONS, TGT)
    const float* __restrict__ loc,
    const float* __restrict__ scale,
    float*       __restrict__ out)      // (BATCH, TGT)
{
    __shared__ int list[LISTMAX];

    // XCD swizzle: the 6 n-tile blocks of a station land on one XCD (share z, stations)
    const int bid0 = blockIdx.x;
    const int bid  = (bid0 & 7) * CPX + (bid0 >> 3);
    const int s    = bid / NTILE_N;
    const int n0   = (bid - s * NTILE_N) * 16;

    const int l  = threadIdx.x;       // 0..63
    const int lr = l & 15;
    const int kh = (l >> 4) * 8;      // k sub-offset within a K=32 step

    // ---- per-wave list build: ballot scan of stations[] (coalesced, L2-hot) ----
    int m = 0;
    const unsigned long long lanelt = (1ull << l) - 1ull;
    for (int c = 0; c < BATCH; c += 64) {
        const bool match = (stations[c + l] == s);
        const unsigned long long msk = __ballot(match);
        if (match) {
            const int pos = m + (int)__popcll(msk & lanelt);
            if (pos < LISTMAX) list[pos] = c + l;
        }
        m += (int)__popcll(msk);
    }
    if (m == 0) return;
    if (m > LISTMAX) m = LISTMAX;

    const float lc = loc[s], sc = scale[s], inv = 1.0f / sc;
    const float nb = -lc * inv;

    const float* wrow  = W + ((size_t)s * TGT + n0 + lr) * CTX + kh;
    const float  biasv = bias[(size_t)s * TGT + n0 + lr];

    const int ntiles = (m + 15) >> 4;
    const int rbase  = (l >> 4) * 4;  // D row base for this lane

    for (int t0 = 0; t0 < ntiles; t0 += 2) {
        int j0 = t0 * 16 + lr;        if (j0 > m - 1) j0 = m - 1;
        int j1 = t0 * 16 + 16 + lr;   if (j1 > m - 1) j1 = m - 1;
        const float* zr0 = z + (size_t)list[j0] * CTX + kh;
        const float* zr1 = z + (size_t)list[j1] * CTX + kh;
        const bool two = (t0 + 1 < ntiles);

        f32x4 acc0 = {0.f, 0.f, 0.f, 0.f};
        f32x4 acc1 = {0.f, 0.f, 0.f, 0.f};

#pragma unroll 4
        for (int kk = 0; kk < 12; ++kk) {
            const int ko = kk * 32;
            float4 wv0 = *reinterpret_cast<const float4*>(wrow + ko);
            float4 wv1 = *reinterpret_cast<const float4*>(wrow + ko + 4);
            float4 a00 = *reinterpret_cast<const float4*>(zr0 + ko);
            float4 a01 = *reinterpret_cast<const float4*>(zr0 + ko + 4);

            bf16x8 bhi, blo;
            cvt_hilo(wv0, wv1, bhi, blo);
            bf16x8 afr0 = cvt_norm(a00, a01, inv, nb);

            acc0 = __builtin_amdgcn_mfma_f32_16x16x32_bf16(afr0, bhi, acc0, 0, 0, 0);
            acc0 = __builtin_amdgcn_mfma_f32_16x16x32_bf16(afr0, blo, acc0, 0, 0, 0);

            if (two) {
                float4 a10 = *reinterpret_cast<const float4*>(zr1 + ko);
                float4 a11 = *reinterpret_cast<const float4*>(zr1 + ko + 4);
                bf16x8 afr1 = cvt_norm(a10, a11, inv, nb);
                acc1 = __builtin_amdgcn_mfma_f32_16x16x32_bf16(afr1, bhi, acc1, 0, 0, 0);
                acc1 = __builtin_amdgcn_mfma_f32_16x16x32_bf16(afr1, blo, acc1, 0, 0, 0);
            }
        }

        // epilogue: denorm + softplus; stores guarded by m
#pragma unroll
        for (int r = 0; r < 4; ++r) {
            const int j = t0 * 16 + rbase + r;
            if (j < m) {
                const int id = list[j];
                float v = (acc0[r] + biasv) * sc + lc;
                out[(size_t)id * TGT + n0 + lr] =
                    fmaxf(v, 0.f) + log1pf(expf(-fabsf(v)));
            }
        }
        if (two) {
#pragma unroll
            for (int r = 0; r < 4; ++r) {
                const int j = t0 * 16 + 16 + rbase + r;
                if (j < m) {
                    const int id = list[j];
                    float v = (acc1[r] + biasv) * sc + lc;
                    out[(size_t)id * TGT + n0 + lr] =
                        fmaxf(v, 0.f) + log1pf(expf(-fabsf(v)));
                }
            }
        }
    }
}

extern "C" void kernel_launch(void* const* d_in, const int* in_sizes, int n_in,
                              void* d_out, int out_size, void* d_ws, size_t ws_size,
                              hipStream_t stream) {
    const float* z        = (const float*)d_in[0];
    const int*   stations = (const int*)  d_in[1];
    const float* W        = (const float*)d_in[2];
    const float* bias     = (const float*)d_in[3];
    const float* loc      = (const float*)d_in[4];
    const float* scale    = (const float*)d_in[5];
    float* out = (float*)d_out;

    nlinear_fused<<<NBLK, 64, 0, stream>>>(z, stations, W, bias, loc, scale, out);
}

// Round 12
// 33.988 us; speedup vs baseline: 1.2002x; 1.2002x over previous
//
#include <hip/hip_runtime.h>
#include <hip/hip_bf16.h>
#include <math.h>

#define N_STATIONS 276
#define CTX 384
#define TGT 96
#define BATCH 4096
#define NTILE_N 6                       // 96 cols / 16
#define KSPLIT 2
#define KHALF 192                       // K per split
#define NSTEP 6                         // K=32 steps per half
#define NTASK (N_STATIONS * NTILE_N * KSPLIT)   // 3312 = 8*414
#define CPX2 (NTASK / 8)                // 414 (bijective XCD swizzle)

typedef __attribute__((ext_vector_type(8))) short bf16x8;   // 8 bf16 (4 VGPRs)
typedef __attribute__((ext_vector_type(4))) float f32x4;    // MFMA acc

__device__ __forceinline__ short f2bf(float f) {            // HW RNE cvt
    return (short)__builtin_bit_cast(unsigned short, __float2bfloat16(f));
}
__device__ __forceinline__ float bf2f(short h) {
    unsigned u = ((unsigned)(unsigned short)h) << 16;
    return __builtin_bit_cast(float, u);
}
__device__ __forceinline__ void cvt_hilo(float4 a, float4 b, bf16x8& hi, bf16x8& lo) {
    float f[8] = {a.x, a.y, a.z, a.w, b.x, b.y, b.z, b.w};
#pragma unroll
    for (int i = 0; i < 8; ++i) {
        short h = f2bf(f[i]);
        hi[i] = h;
        lo[i] = f2bf(f[i] - bf2f(h));
    }
}
__device__ __forceinline__ bf16x8 cvt_norm(float4 a, float4 b, float inv, float nb) {
    float f[8] = {a.x, a.y, a.z, a.w, b.x, b.y, b.z, b.w};
    bf16x8 r;
#pragma unroll
    for (int i = 0; i < 8; ++i) r[i] = f2bf(fmaf(f[i], inv, nb));
    return r;
}

// ---------- kernel 1: per-station sample lists (compact) ----------
__global__ __launch_bounds__(1024) void build_lists(
    const int* __restrict__ stations,
    int* __restrict__ order,    // (BATCH,)
    int* __restrict__ offsets)  // (N_STATIONS+1,)
{
    __shared__ int cnt[N_STATIONS];
    __shared__ int cnt2[N_STATIONS];
    __shared__ int poff[N_STATIONS + 1];
    const int tid = threadIdx.x;
    for (int i = tid; i < N_STATIONS; i += 1024) { cnt[i] = 0; cnt2[i] = 0; }
    __syncthreads();
    for (int b = tid; b < BATCH; b += 1024) atomicAdd(&cnt[stations[b]], 1);
    __syncthreads();
    if (tid < 64) {   // wave-parallel inclusive scan, 5 chunks of 64
        int run = 0;
        for (int base = 0; base < N_STATIONS; base += 64) {
            const int i = base + tid;
            int v = (i < N_STATIONS) ? cnt[i] : 0;
#pragma unroll
            for (int off = 1; off < 64; off <<= 1) {
                int u = __shfl_up(v, off, 64);
                if (tid >= off) v += u;
            }
            if (i < N_STATIONS) poff[i + 1] = run + v;
            run += __shfl(v, 63, 64);
        }
        if (tid == 0) poff[0] = 0;
    }
    __syncthreads();
    for (int b = tid; b < BATCH; b += 1024) {
        int s = stations[b];
        int p = atomicAdd(&cnt2[s], 1);
        order[poff[s] + p] = b;
    }
    if (tid <= N_STATIONS) offsets[tid] = poff[tid];
}

// ---------- kernel 2: split-K MFMA, one wave per (station, n-tile, k-half) ----------
// W fragments hoisted (read once per wave, 6 hi + 6 lo bf16x8); z loads fully
// unrolled per half. Partials atomicAdd'ed into pre-zeroed out[].
__global__ __launch_bounds__(64, 1) void nlinear_splitk(
    const float* __restrict__ z,        // (BATCH, CTX)
    const int*   __restrict__ order,
    const int*   __restrict__ offsets,
    const float* __restrict__ W,        // (N_STATIONS, TGT, CTX)
    const float* __restrict__ loc,
    const float* __restrict__ scale,
    float*       __restrict__ out)      // (BATCH, TGT) accumulator, pre-zeroed
{
    const int bid0 = blockIdx.x;
    const int bid  = (bid0 & 7) * CPX2 + (bid0 >> 3);   // XCD swizzle (bijective)
    const int half = bid & 1;
    const int task = bid >> 1;
    const int s    = task / NTILE_N;
    const int n0   = (task - s * NTILE_N) * 16;

    const int start = offsets[s];
    const int m     = offsets[s + 1] - start;
    if (m == 0) return;

    const int l  = threadIdx.x;       // 0..63
    const int lr = l & 15;
    const int kh = (l >> 4) * 8;      // k sub-offset within a K=32 step

    const float lc  = loc[s];
    const float inv = 1.0f / scale[s];
    const float nb  = -lc * inv;

    // ---- hoisted W fragments for this (n-tile, k-half): read once ----
    const float* wrow = W + ((size_t)s * TGT + n0 + lr) * CTX + half * KHALF + kh;
    bf16x8 bhi[NSTEP], blo[NSTEP];
#pragma unroll
    for (int kk = 0; kk < NSTEP; ++kk) {
        float4 w0 = *reinterpret_cast<const float4*>(wrow + kk * 32);
        float4 w1 = *reinterpret_cast<const float4*>(wrow + kk * 32 + 4);
        cvt_hilo(w0, w1, bhi[kk], blo[kk]);
    }

    const int ntiles = (m + 15) >> 4;
    const int rbase  = (l >> 4) * 4;  // D row base for this lane

    for (int t = 0; t < ntiles; ++t) {
        int j = t * 16 + lr; if (j > m - 1) j = m - 1;
        const float* zr = z + (size_t)order[start + j] * CTX + half * KHALF + kh;

        f32x4 acc = {0.f, 0.f, 0.f, 0.f};
#pragma unroll
        for (int kk = 0; kk < NSTEP; ++kk) {
            float4 a0 = *reinterpret_cast<const float4*>(zr + kk * 32);
            float4 a1 = *reinterpret_cast<const float4*>(zr + kk * 32 + 4);
            bf16x8 af = cvt_norm(a0, a1, inv, nb);
            acc = __builtin_amdgcn_mfma_f32_16x16x32_bf16(af, bhi[kk], acc, 0, 0, 0);
            acc = __builtin_amdgcn_mfma_f32_16x16x32_bf16(af, blo[kk], acc, 0, 0, 0);
        }
#pragma unroll
        for (int r = 0; r < 4; ++r) {
            const int jj = t * 16 + rbase + r;
            if (jj < m) {
                const int oid = order[start + jj];
                atomicAdd(&out[(size_t)oid * TGT + n0 + lr], acc[r]);
            }
        }
    }
}

// ---------- kernel 3: epilogue (bias + denorm + softplus), in place ----------
__global__ __launch_bounds__(256) void epilogue(
    const int*   __restrict__ stations,
    const float* __restrict__ bias,
    const float* __restrict__ loc,
    const float* __restrict__ scale,
    float*       __restrict__ out)
{
    const int gid = blockIdx.x * 256 + threadIdx.x;
    if (gid >= BATCH * TGT) return;
    const int id = gid / TGT;
    const int c  = gid - id * TGT;
    const int s  = stations[id];
    float v = (out[gid] + bias[(size_t)s * TGT + c]) * scale[s] + loc[s];
    out[gid] = fmaxf(v, 0.f) + log1pf(expf(-fabsf(v)));
}

extern "C" void kernel_launch(void* const* d_in, const int* in_sizes, int n_in,
                              void* d_out, int out_size, void* d_ws, size_t ws_size,
                              hipStream_t stream) {
    const float* z        = (const float*)d_in[0];
    const int*   stations = (const int*)  d_in[1];
    const float* W        = (const float*)d_in[2];
    const float* bias     = (const float*)d_in[3];
    const float* loc      = (const float*)d_in[4];
    const float* scale    = (const float*)d_in[5];
    float* out = (float*)d_out;

    int* order   = (int*)d_ws;
    int* offsets = order + BATCH;

    hipMemsetAsync(out, 0, (size_t)BATCH * TGT * sizeof(float), stream);
    build_lists<<<1, 1024, 0, stream>>>(stations, order, offsets);
    nlinear_splitk<<<NTASK, 64, 0, stream>>>(z, order, offsets, W, loc, scale, out);
    epilogue<<<(BATCH * TGT + 255) / 256, 256, 0, stream>>>(stations, bias, loc, scale, out);
}